// Round 2
// baseline (735.320 us; speedup 1.0000x reference)
//
#include <hip/hip_runtime.h>
#include <hip/hip_bf16.h>

// Problem constants (fixed by setup_inputs)
#define T_STEPS 512
#define BATCH   256
#define NN      128                 // n
#define NEMB    1024                // N
#define M_ROWS  (T_STEPS * BATCH)   // 131072
#define NOISE_K 0.13416407864998738f  // sqrt(2/alpha * sigma^2)

typedef short s16x8 __attribute__((ext_vector_type(8)));
typedef float f32x4 __attribute__((ext_vector_type(4)));

__device__ __forceinline__ unsigned short f2bf(float f) {
  union { float f; unsigned u; } v; v.f = f;
  unsigned r = v.u + 0x7fffu + ((v.u >> 16) & 1u);  // RNE
  return (unsigned short)(r >> 16);
}
__device__ __forceinline__ float bf2f(unsigned short s) {
  union { unsigned u; float f; } v; v.u = ((unsigned)s) << 16;
  return v.f;
}

// ---------------------------------------------------------------------------
// Kernel 1: leaky-RNN recurrence. 2 batches per block (512 threads).
// Per batch: 256 threads, tid8 = i*2 + h; thread sums W_rec[i, h*64..h*64+63].
// x double-buffered in LDS with +4-float pad between halves (bank-disjoint
// reads for h=0 vs h=1). ONE barrier per step. 4 accumulators.
// states (bf16) written to ws in (T, B, n) layout; row m = t*B + b.
// ---------------------------------------------------------------------------
__global__ __launch_bounds__(512) void rnn_step_kernel(
    const float* __restrict__ u,          // (6, T, B)
    const float* __restrict__ rec_noise,  // (B, T, n)
    const float* __restrict__ inp_noise,  // (B, T, 6)
    const float* __restrict__ W_inp,      // (n, 6)
    const float* __restrict__ W_rec,      // (n, n)
    unsigned short* __restrict__ states)  // (T, B, n) bf16
{
  const int tid = threadIdx.x;
  const int bl  = tid >> 8;            // local batch 0/1
  const int b   = blockIdx.x * 2 + bl;
  const int t8  = tid & 255;
  const int i   = t8 >> 1;
  const int h   = t8 & 1;

  // x layout per (batch, buf): x[0..63] at [0..63], x[64..127] at [68..131]
  __shared__ float xbuf[2][2][136];
  __shared__ float u_s[2][2][8];

  // W_rec half-row into registers (64 fp32)
  float4 w[16];
  {
    const float4* wr = (const float4*)(W_rec + i * NN + h * 64);
    #pragma unroll
    for (int c = 0; c < 16; ++c) w[c] = wr[c];
  }
  float winp[6];
  #pragma unroll
  for (int j = 0; j < 6; ++j) winp[j] = W_inp[i * 6 + j];

  if (t8 < 136) xbuf[bl][0][t8] = 0.f;
  if (h == 0) states[(0 * BATCH + b) * NN + i] = 0;  // t=0 state is zero

  // prologue: step-0 inputs
  float rn_c = rec_noise[(b * T_STEPS + 0) * NN + i];
  if (t8 < 6) {
    float uu   = u[t8 * (T_STEPS * BATCH) + 0 * BATCH + b];
    float in_n = inp_noise[(b * T_STEPS + 0) * 6 + t8];
    u_s[bl][0][t8] = uu + NOISE_K * in_n;
  }
  __syncthreads();

  float xr = 0.f;  // private copy of x[i]
  for (int t = 0; t < T_STEPS - 1; ++t) {
    const int cur = t & 1, nxt = cur ^ 1;

    // prefetch t+1 inputs (t+1 <= 511 always in-bounds)
    float rn_n = rec_noise[(b * T_STEPS + (t + 1)) * NN + i];
    float uu_n = 0.f, in_nn = 0.f;
    if (t8 < 6) {
      uu_n  = u[t8 * (T_STEPS * BATCH) + (t + 1) * BATCH + b];
      in_nn = inp_noise[(b * T_STEPS + (t + 1)) * 6 + t8];
    }

    // matvec half-row: conflict-free reads (h=0 banks 4c..4c+3, h=1 4c+4..4c+7)
    const float* xb = &xbuf[bl][cur][h * 68];
    float a0 = 0.f, a1 = 0.f, a2 = 0.f, a3 = 0.f;
    #pragma unroll
    for (int c = 0; c < 16; c += 4) {
      float4 v0 = *(const float4*)&xb[(c + 0) * 4];
      float4 v1 = *(const float4*)&xb[(c + 1) * 4];
      float4 v2 = *(const float4*)&xb[(c + 2) * 4];
      float4 v3 = *(const float4*)&xb[(c + 3) * 4];
      a0 = fmaf(w[c+0].x, v0.x, a0); a0 = fmaf(w[c+0].y, v0.y, a0);
      a0 = fmaf(w[c+0].z, v0.z, a0); a0 = fmaf(w[c+0].w, v0.w, a0);
      a1 = fmaf(w[c+1].x, v1.x, a1); a1 = fmaf(w[c+1].y, v1.y, a1);
      a1 = fmaf(w[c+1].z, v1.z, a1); a1 = fmaf(w[c+1].w, v1.w, a1);
      a2 = fmaf(w[c+2].x, v2.x, a2); a2 = fmaf(w[c+2].y, v2.y, a2);
      a2 = fmaf(w[c+2].z, v2.z, a2); a2 = fmaf(w[c+2].w, v2.w, a2);
      a3 = fmaf(w[c+3].x, v3.x, a3); a3 = fmaf(w[c+3].y, v3.y, a3);
      a3 = fmaf(w[c+3].z, v3.z, a3); a3 = fmaf(w[c+3].w, v3.w, a3);
    }
    float acc = (a0 + a1) + (a2 + a3);
    acc += __shfl_xor(acc, 1);   // combine h=0 and h=1 halves

    float inp = 0.f;
    #pragma unroll
    for (int j = 0; j < 6; ++j) inp = fmaf(winp[j], u_s[bl][cur][j], inp);

    float pre = acc + inp;
    float r   = pre > 0.f ? pre : 0.f;
    float xn  = 0.9f * xr + 0.1f * (r + NOISE_K * rn_c);
    xr = xn;
    rn_c = rn_n;

    if (h == 0) {
      xbuf[bl][nxt][i + ((i >> 6) << 2)] = xn;   // i<64 -> i ; i>=64 -> 68+(i-64)
      states[((t + 1) * BATCH + b) * NN + i] = f2bf(xn);
    }
    if (t8 < 6) u_s[bl][nxt][t8] = uu_n + NOISE_K * in_nn;

    __syncthreads();  // new x / u_s visible; also protects cur from next write
  }
}

// ---------------------------------------------------------------------------
// Kernel 2: states_embedded = states @ q, written transposed: out[j*M + m].
// Tile: 128 m x 64 j per block, 4 waves (each 32 m x 64 j), K = 128.
// q staged in LDS as bf16, XOR-swizzled on 16B units for conflict-free b128.
// A fragments loaded straight from global (L2-reused across the 16 j-tiles).
// ---------------------------------------------------------------------------
__global__ __launch_bounds__(256) void emb_kernel(
    const unsigned short* __restrict__ states,  // (M, n) bf16
    const float* __restrict__ q,                // (n, NEMB)
    float* __restrict__ out)                    // out[j*M + m]
{
  const int jt  = blockIdx.x;   // 0..15  (fast dim -> j-tiles of one m-panel co-resident)
  const int mt  = blockIdx.y;   // 0..1023
  const int tid = threadIdx.x;
  const int w   = tid >> 6;
  const int l   = tid & 63;
  const int lg  = l >> 4;       // 0..3
  const int lr  = l & 15;

  __shared__ unsigned short qt[64 * 128];  // [j][k], swizzled, 16 KB

  // stage q tile -> bf16 LDS (coalesced global reads)
  {
    const int j  = tid & 63;
    const int k0 = tid >> 6;
    #pragma unroll
    for (int kk = k0; kk < 128; kk += 4) {
      float v = q[kk * NEMB + jt * 64 + j];
      int k8 = kk >> 3, e = kk & 7;
      qt[j * 128 + ((k8 ^ (j & 7)) << 3) + e] = f2bf(v);
    }
  }

  // A fragments from global: row = l&15, k-chunk = (l>>4)*8 within each K=32
  s16x8 afrag[2][4];
  #pragma unroll
  for (int mf = 0; mf < 2; ++mf) {
    const int m = mt * 128 + w * 32 + mf * 16 + lr;
    const unsigned short* arow = states + m * NN;
    #pragma unroll
    for (int kc = 0; kc < 4; ++kc)
      afrag[mf][kc] = *(const s16x8*)(arow + kc * 32 + lg * 8);
  }
  __syncthreads();

  f32x4 acc[2][4] = {};
  #pragma unroll
  for (int kc = 0; kc < 4; ++kc) {
    s16x8 bfrag[4];
    #pragma unroll
    for (int jf = 0; jf < 4; ++jf) {
      const int jl = jf * 16 + lr;
      bfrag[jf] = *(const s16x8*)(qt + jl * 128 + ((((kc << 2) + lg) ^ (jl & 7)) << 3));
    }
    #pragma unroll
    for (int mf = 0; mf < 2; ++mf)
      #pragma unroll
      for (int jf = 0; jf < 4; ++jf)
        acc[mf][jf] = __builtin_amdgcn_mfma_f32_16x16x32_bf16(
            afrag[mf][kc], bfrag[jf], acc[mf][jf], 0, 0, 0);
  }

  // epilogue: per-lane float4 along m (D: col=lane&15 -> j, row=(lane>>4)*4+reg -> m)
  #pragma unroll
  for (int mf = 0; mf < 2; ++mf) {
    const int m = mt * 128 + w * 32 + mf * 16 + lg * 4;
    #pragma unroll
    for (int jf = 0; jf < 4; ++jf) {
      const long j = jt * 64 + jf * 16 + lr;
      *(f32x4*)&out[j * M_ROWS + m] = acc[mf][jf];
    }
  }
}

// ---------------------------------------------------------------------------
// Kernel 3: outputs = states @ W_out^T  ->  out[(1024+j)*M + m]
// ---------------------------------------------------------------------------
__global__ __launch_bounds__(256) void wout_kernel(
    const unsigned short* __restrict__ states,  // (M, n) bf16
    const float* __restrict__ W_out,            // (2, n)
    float* __restrict__ out)
{
  __shared__ float wo[2 * NN];
  const int tid = threadIdx.x;
  wo[tid] = W_out[tid];
  __syncthreads();

  const int m = blockIdx.x * 256 + tid;
  const unsigned short* row = states + (size_t)m * NN;
  float a0 = 0.f, a1 = 0.f;
  #pragma unroll
  for (int c = 0; c < 16; ++c) {
    s16x8 v = *(const s16x8*)(row + c * 8);
    #pragma unroll
    for (int e = 0; e < 8; ++e) {
      float x = bf2f((unsigned short)v[e]);
      a0 = fmaf(x, wo[c * 8 + e], a0);
      a1 = fmaf(x, wo[NN + c * 8 + e], a1);
    }
  }
  out[(long)1024 * M_ROWS + m] = a0;
  out[(long)1025 * M_ROWS + m] = a1;
}

extern "C" void kernel_launch(void* const* d_in, const int* in_sizes, int n_in,
                              void* d_out, int out_size, void* d_ws, size_t ws_size,
                              hipStream_t stream) {
  const float* u         = (const float*)d_in[0];
  const float* rec_noise = (const float*)d_in[1];
  const float* inp_noise = (const float*)d_in[2];
  const float* W_inp     = (const float*)d_in[3];
  const float* W_rec     = (const float*)d_in[4];
  const float* W_out     = (const float*)d_in[5];
  const float* q         = (const float*)d_in[6];
  float* out = (float*)d_out;
  unsigned short* states = (unsigned short*)d_ws;  // (T, B, n) bf16 = 33.6 MB

  rnn_step_kernel<<<dim3(BATCH / 2), dim3(512), 0, stream>>>(
      u, rec_noise, inp_noise, W_inp, W_rec, states);

  dim3 g2(NEMB / 64, M_ROWS / 128);  // (16, 1024), jt fastest for A-panel L2 reuse
  emb_kernel<<<g2, dim3(256), 0, stream>>>(states, q, out);

  wout_kernel<<<dim3(M_ROWS / 256), dim3(256), 0, stream>>>(states, W_out, out);
}

// Round 3
// 470.517 us; speedup vs baseline: 1.5628x; 1.5628x over previous
//
#include <hip/hip_runtime.h>
#include <hip/hip_bf16.h>

// Problem constants (fixed by setup_inputs)
#define T_STEPS 512
#define BATCH   256
#define NN      128                 // n
#define NEMB    1024                // N
#define M_ROWS  (T_STEPS * BATCH)   // 131072
#define NOISE_K 0.13416407864998738f  // sqrt(2/alpha * sigma^2)
#define CH      8                   // steps per staged chunk
#define NCHUNK  (T_STEPS / CH)      // 64 (last chunk runs 7 steps)

typedef short s16x8 __attribute__((ext_vector_type(8)));
typedef float f32x4 __attribute__((ext_vector_type(4)));

__device__ __forceinline__ unsigned short f2bf(float f) {
  union { float f; unsigned u; } v; v.f = f;
  unsigned r = v.u + 0x7fffu + ((v.u >> 16) & 1u);  // RNE
  return (unsigned short)(r >> 16);
}
__device__ __forceinline__ float bf2f(unsigned short s) {
  union { unsigned u; float f; } v; v.u = ((unsigned)s) << 16;
  return v.f;
}

// ---------------------------------------------------------------------------
// Kernel 1: leaky-RNN recurrence. One block (256 thr) per batch element.
// tid = i*2 + h; thread sums W_rec[i, h*64 .. h*64+63] (4 accumulators,
// chain depth 16), shfl_xor(1) combines halves. x double-buffered in LDS.
// Noise/input stream staged in 8-step double-buffered LDS chunks: loads for
// chunk c+1 issued at chunk-c start (8-step = ~3000 cyc prefetch distance),
// committed to LDS at the chunk boundary -> no per-step vmcnt stall.
// states (bf16) written to ws in (T, B, n) layout; row m = t*B + b.
// ---------------------------------------------------------------------------
__global__ __launch_bounds__(256) void rnn_step_kernel(
    const float* __restrict__ u,          // (6, T, B)
    const float* __restrict__ rec_noise,  // (B, T, n)
    const float* __restrict__ inp_noise,  // (B, T, 6)
    const float* __restrict__ W_inp,      // (n, 6)
    const float* __restrict__ W_rec,      // (n, n)
    unsigned short* __restrict__ states)  // (T, B, n) bf16
{
  const int b   = blockIdx.x;
  const int tid = threadIdx.x;
  const int i   = tid >> 1;
  const int h   = tid & 1;

  // x per buf: x[0..63] at [0..63], x[64..127] at [68..131]
  __shared__ float xbuf[2][136];
  __shared__ float rns[2][CH * NN];   // staged rec_noise chunk
  __shared__ float us[2][CH][8];      // staged (u + K*inp_noise) chunk

  // W_rec half-row into registers (64 fp32)
  float4 w[16];
  {
    const float4* wr = (const float4*)(W_rec + i * NN + h * 64);
    #pragma unroll
    for (int c = 0; c < 16; ++c) w[c] = wr[c];
  }
  float winp[6];
  #pragma unroll
  for (int j = 0; j < 6; ++j) winp[j] = W_inp[i * 6 + j];

  const int ts6 = tid / 6, j6 = tid - ts6 * 6;  // (step, input) map for tid<48

  if (tid < 136) xbuf[0][tid] = 0.f;
  if (h == 0) states[b * NN + i] = 0;  // t=0 state is zero

  // prologue: stage chunk 0 (t = 0..7)
  {
    const f32x4* src = (const f32x4*)(rec_noise + (size_t)b * T_STEPS * NN);
    *(f32x4*)&rns[0][tid * 4] = src[tid];
    if (tid < 48) {
      float uu = u[j6 * (T_STEPS * BATCH) + ts6 * BATCH + b];
      float in = inp_noise[((size_t)b * T_STEPS + ts6) * 6 + j6];
      us[0][ts6][j6] = uu + NOISE_K * in;
    }
  }
  __syncthreads();

  float xr = 0.f;  // private copy of x[i]
  for (int c = 0; c < NCHUNK; ++c) {
    const int cb = c & 1;

    // issue prefetch for chunk c+1 (lands during the 8 steps below)
    f32x4 rn_pf = {0.f, 0.f, 0.f, 0.f};
    float u_pf = 0.f, in_pf = 0.f;
    if (c < NCHUNK - 1) {
      const f32x4* src =
          (const f32x4*)(rec_noise + ((size_t)b * T_STEPS + (c + 1) * CH) * NN);
      rn_pf = src[tid];
      if (tid < 48) {
        const int tt = (c + 1) * CH + ts6;
        u_pf  = u[j6 * (T_STEPS * BATCH) + tt * BATCH + b];
        in_pf = inp_noise[((size_t)b * T_STEPS + tt) * 6 + j6];
      }
    }

    #pragma unroll
    for (int ts = 0; ts < CH; ++ts) {
      const int t = c * CH + ts;
      if (t > T_STEPS - 2) break;          // uniform: only trims last chunk
      const int cur = ts & 1, nxt = cur ^ 1;  // c*CH is even -> parity = ts&1

      // matvec half-row: h=0 lanes broadcast-read [0..63], h=1 [68..131]
      const float* xb = &xbuf[cur][h * 68];
      float a0 = 0.f, a1 = 0.f, a2 = 0.f, a3 = 0.f;
      #pragma unroll
      for (int cc = 0; cc < 16; cc += 4) {
        float4 v0 = *(const float4*)&xb[(cc + 0) * 4];
        float4 v1 = *(const float4*)&xb[(cc + 1) * 4];
        float4 v2 = *(const float4*)&xb[(cc + 2) * 4];
        float4 v3 = *(const float4*)&xb[(cc + 3) * 4];
        a0 = fmaf(w[cc+0].x, v0.x, a0); a0 = fmaf(w[cc+0].y, v0.y, a0);
        a0 = fmaf(w[cc+0].z, v0.z, a0); a0 = fmaf(w[cc+0].w, v0.w, a0);
        a1 = fmaf(w[cc+1].x, v1.x, a1); a1 = fmaf(w[cc+1].y, v1.y, a1);
        a1 = fmaf(w[cc+1].z, v1.z, a1); a1 = fmaf(w[cc+1].w, v1.w, a1);
        a2 = fmaf(w[cc+2].x, v2.x, a2); a2 = fmaf(w[cc+2].y, v2.y, a2);
        a2 = fmaf(w[cc+2].z, v2.z, a2); a2 = fmaf(w[cc+2].w, v2.w, a2);
        a3 = fmaf(w[cc+3].x, v3.x, a3); a3 = fmaf(w[cc+3].y, v3.y, a3);
        a3 = fmaf(w[cc+3].z, v3.z, a3); a3 = fmaf(w[cc+3].w, v3.w, a3);
      }
      float acc = (a0 + a1) + (a2 + a3);
      acc += __shfl_xor(acc, 1);   // combine h=0 and h=1 halves

      float inp = 0.f;
      #pragma unroll
      for (int j = 0; j < 6; ++j) inp = fmaf(winp[j], us[cb][ts][j], inp);

      const float pre = acc + inp;
      const float r   = pre > 0.f ? pre : 0.f;
      const float xn  = 0.9f * xr + 0.1f * (r + NOISE_K * rns[cb][ts * NN + i]);
      xr = xn;

      if (h == 0) {
        xbuf[nxt][i + ((i >> 6) << 2)] = xn;  // i<64 -> i ; i>=64 -> 68+(i-64)
        states[((t + 1) * BATCH + b) * NN + i] = f2bf(xn);
      }
      __syncthreads();  // new x visible before next step
    }

    // commit prefetched chunk to the other LDS buffer
    if (c < NCHUNK - 1) {
      *(f32x4*)&rns[cb ^ 1][tid * 4] = rn_pf;
      if (tid < 48) us[cb ^ 1][ts6][j6] = u_pf + NOISE_K * in_pf;
      __syncthreads();
    }
  }
}

// ---------------------------------------------------------------------------
// Kernel 2: states_embedded = states @ q, written transposed: out[j*M + m].
// Tile: 128 m x 64 j per block, 4 waves (each 32 m x 64 j), K = 128.
// q staged in LDS as bf16, XOR-swizzled on 16B units for conflict-free b128.
// A fragments loaded straight from global (L2-reused across the 16 j-tiles).
// ---------------------------------------------------------------------------
__global__ __launch_bounds__(256) void emb_kernel(
    const unsigned short* __restrict__ states,  // (M, n) bf16
    const float* __restrict__ q,                // (n, NEMB)
    float* __restrict__ out)                    // out[j*M + m]
{
  const int jt  = blockIdx.x;   // 0..15  (fast dim -> j-tiles of one m-panel co-resident)
  const int mt  = blockIdx.y;   // 0..1023
  const int tid = threadIdx.x;
  const int w   = tid >> 6;
  const int l   = tid & 63;
  const int lg  = l >> 4;       // 0..3
  const int lr  = l & 15;

  __shared__ unsigned short qt[64 * 128];  // [j][k], swizzled, 16 KB

  // stage q tile -> bf16 LDS (coalesced global reads)
  {
    const int j  = tid & 63;
    const int k0 = tid >> 6;
    #pragma unroll
    for (int kk = k0; kk < 128; kk += 4) {
      float v = q[kk * NEMB + jt * 64 + j];
      int k8 = kk >> 3, e = kk & 7;
      qt[j * 128 + ((k8 ^ (j & 7)) << 3) + e] = f2bf(v);
    }
  }

  // A fragments from global: row = l&15, k-chunk = (l>>4)*8 within each K=32
  s16x8 afrag[2][4];
  #pragma unroll
  for (int mf = 0; mf < 2; ++mf) {
    const int m = mt * 128 + w * 32 + mf * 16 + lr;
    const unsigned short* arow = states + m * NN;
    #pragma unroll
    for (int kc = 0; kc < 4; ++kc)
      afrag[mf][kc] = *(const s16x8*)(arow + kc * 32 + lg * 8);
  }
  __syncthreads();

  f32x4 acc[2][4] = {};
  #pragma unroll
  for (int kc = 0; kc < 4; ++kc) {
    s16x8 bfrag[4];
    #pragma unroll
    for (int jf = 0; jf < 4; ++jf) {
      const int jl = jf * 16 + lr;
      bfrag[jf] = *(const s16x8*)(qt + jl * 128 + ((((kc << 2) + lg) ^ (jl & 7)) << 3));
    }
    #pragma unroll
    for (int mf = 0; mf < 2; ++mf)
      #pragma unroll
      for (int jf = 0; jf < 4; ++jf)
        acc[mf][jf] = __builtin_amdgcn_mfma_f32_16x16x32_bf16(
            afrag[mf][kc], bfrag[jf], acc[mf][jf], 0, 0, 0);
  }

  // epilogue: per-lane float4 along m (D: col=lane&15 -> j, row=(lane>>4)*4+reg -> m)
  #pragma unroll
  for (int mf = 0; mf < 2; ++mf) {
    const int m = mt * 128 + w * 32 + mf * 16 + lg * 4;
    #pragma unroll
    for (int jf = 0; jf < 4; ++jf) {
      const long j = jt * 64 + jf * 16 + lr;
      *(f32x4*)&out[j * M_ROWS + m] = acc[mf][jf];
    }
  }
}

// ---------------------------------------------------------------------------
// Kernel 3: outputs = states @ W_out^T  ->  out[(1024+j)*M + m]
// ---------------------------------------------------------------------------
__global__ __launch_bounds__(256) void wout_kernel(
    const unsigned short* __restrict__ states,  // (M, n) bf16
    const float* __restrict__ W_out,            // (2, n)
    float* __restrict__ out)
{
  __shared__ float wo[2 * NN];
  const int tid = threadIdx.x;
  wo[tid] = W_out[tid];
  __syncthreads();

  const int m = blockIdx.x * 256 + tid;
  const unsigned short* row = states + (size_t)m * NN;
  float a0 = 0.f, a1 = 0.f;
  #pragma unroll
  for (int c = 0; c < 16; ++c) {
    s16x8 v = *(const s16x8*)(row + c * 8);
    #pragma unroll
    for (int e = 0; e < 8; ++e) {
      float x = bf2f((unsigned short)v[e]);
      a0 = fmaf(x, wo[c * 8 + e], a0);
      a1 = fmaf(x, wo[NN + c * 8 + e], a1);
    }
  }
  out[(long)1024 * M_ROWS + m] = a0;
  out[(long)1025 * M_ROWS + m] = a1;
}

extern "C" void kernel_launch(void* const* d_in, const int* in_sizes, int n_in,
                              void* d_out, int out_size, void* d_ws, size_t ws_size,
                              hipStream_t stream) {
  const float* u         = (const float*)d_in[0];
  const float* rec_noise = (const float*)d_in[1];
  const float* inp_noise = (const float*)d_in[2];
  const float* W_inp     = (const float*)d_in[3];
  const float* W_rec     = (const float*)d_in[4];
  const float* W_out     = (const float*)d_in[5];
  const float* q         = (const float*)d_in[6];
  float* out = (float*)d_out;
  unsigned short* states = (unsigned short*)d_ws;  // (T, B, n) bf16 = 33.6 MB

  rnn_step_kernel<<<dim3(BATCH), dim3(256), 0, stream>>>(
      u, rec_noise, inp_noise, W_inp, W_rec, states);

  dim3 g2(NEMB / 64, M_ROWS / 128);  // (16, 1024), jt fastest for A-panel L2 reuse
  emb_kernel<<<g2, dim3(256), 0, stream>>>(states, q, out);

  wout_kernel<<<dim3(M_ROWS / 256), dim3(256), 0, stream>>>(states, W_out, out);
}

// Round 4
// 457.480 us; speedup vs baseline: 1.6073x; 1.0285x over previous
//
#include <hip/hip_runtime.h>
#include <hip/hip_bf16.h>

// Problem constants (fixed by setup_inputs)
#define T_STEPS 512
#define BATCH   256
#define NN      128                 // n
#define NEMB    1024                // N
#define M_ROWS  (T_STEPS * BATCH)   // 131072
#define NOISE_K 0.13416407864998738f  // sqrt(2/alpha * sigma^2)
#define CH      8                   // steps per staged chunk
#define NCHUNK  (T_STEPS / CH)      // 64 (last chunk runs 7 steps)

typedef short s16x8 __attribute__((ext_vector_type(8)));
typedef float f32x4 __attribute__((ext_vector_type(4)));

__device__ __forceinline__ unsigned short f2bf(float f) {
  union { float f; unsigned u; } v; v.f = f;
  unsigned r = v.u + 0x7fffu + ((v.u >> 16) & 1u);  // RNE
  return (unsigned short)(r >> 16);
}
__device__ __forceinline__ float bf2f(unsigned short s) {
  union { unsigned u; float f; } v; v.u = ((unsigned)s) << 16;
  return v.f;
}

// ---------------------------------------------------------------------------
// Kernel 1: leaky-RNN recurrence. One block (256 thr) per batch element.
// tid = i*2 + h; thread sums W_rec[i, h*64 .. h*64+63].
// __launch_bounds__(256,1): allow ~256 VGPRs so the 64-float W half-row
// STAYS in registers (rounds 1-3 showed VGPR_Count 52-56 -> compiler was
// re-loading W_rec from L2 every step; that was the dominant cost).
// x double-buffered in LDS with +4-float pad between halves. One barrier
// per step. Noise staged in 8-step double-buffered LDS chunks.
// states (bf16) written to ws in (T, B, n) layout; row m = t*B + b.
// ---------------------------------------------------------------------------
__global__ __launch_bounds__(256, 1) void rnn_step_kernel(
    const float* __restrict__ u,          // (6, T, B)
    const float* __restrict__ rec_noise,  // (B, T, n)
    const float* __restrict__ inp_noise,  // (B, T, 6)
    const float* __restrict__ W_inp,      // (n, 6)
    const float* __restrict__ W_rec,      // (n, n)
    unsigned short* __restrict__ states)  // (T, B, n) bf16
{
  const int b   = blockIdx.x;
  const int tid = threadIdx.x;
  const int i   = tid >> 1;
  const int h   = tid & 1;

  // x per buf: x[0..63] at [0..63], x[64..127] at [68..131]
  __shared__ float xbuf[2][136];
  __shared__ float rns[2][CH * NN];   // staged rec_noise chunk
  __shared__ float us[2][CH][8];      // staged (u + K*inp_noise) chunk

  // W_rec half-row in NAMED registers (64 fp32) -- not sinkable
  const float4* wr = (const float4*)(W_rec + i * NN + h * 64);
  const float4 w0 = wr[0],  w1 = wr[1],  w2 = wr[2],  w3 = wr[3];
  const float4 w4 = wr[4],  w5 = wr[5],  w6 = wr[6],  w7 = wr[7];
  const float4 w8 = wr[8],  w9 = wr[9],  wA = wr[10], wB = wr[11];
  const float4 wC = wr[12], wD = wr[13], wE = wr[14], wF = wr[15];

  float winp[6];
  #pragma unroll
  for (int j = 0; j < 6; ++j) winp[j] = W_inp[i * 6 + j];

  const int ts6 = tid / 6, j6 = tid - ts6 * 6;  // (step, input) map for tid<48

  if (tid < 136) xbuf[0][tid] = 0.f;
  if (h == 0) states[b * NN + i] = 0;  // t=0 state is zero

  // prologue: stage chunk 0 (t = 0..7)
  {
    const f32x4* src = (const f32x4*)(rec_noise + (size_t)b * T_STEPS * NN);
    *(f32x4*)&rns[0][tid * 4] = src[tid];
    if (tid < 48) {
      float uu = u[j6 * (T_STEPS * BATCH) + ts6 * BATCH + b];
      float in = inp_noise[((size_t)b * T_STEPS + ts6) * 6 + j6];
      us[0][ts6][j6] = uu + NOISE_K * in;
    }
  }
  __syncthreads();

  float xr = 0.f;  // private copy of x[i]
  for (int c = 0; c < NCHUNK; ++c) {
    const int cb = c & 1;

    // issue prefetch for chunk c+1 (lands during the 8 steps below)
    f32x4 rn_pf = {0.f, 0.f, 0.f, 0.f};
    float u_pf = 0.f, in_pf = 0.f;
    if (c < NCHUNK - 1) {
      const f32x4* src =
          (const f32x4*)(rec_noise + ((size_t)b * T_STEPS + (c + 1) * CH) * NN);
      rn_pf = src[tid];
      if (tid < 48) {
        const int tt = (c + 1) * CH + ts6;
        u_pf  = u[j6 * (T_STEPS * BATCH) + tt * BATCH + b];
        in_pf = inp_noise[((size_t)b * T_STEPS + tt) * 6 + j6];
      }
    }

    #pragma unroll
    for (int ts = 0; ts < CH; ++ts) {
      const int t = c * CH + ts;
      if (t > T_STEPS - 2) break;          // uniform: only trims last chunk
      const int cur = ts & 1, nxt = cur ^ 1;  // c*CH is even -> parity = ts&1

      // matvec half-row: h=0 lanes broadcast-read [0..63], h=1 [68..131]
      const float* xb = &xbuf[cur][h * 68];
      float a0 = 0.f, a1 = 0.f, a2 = 0.f, a3 = 0.f;
      #define STEP4(W, IDX, ACC)                                  \
        { float4 xv = *(const float4*)&xb[(IDX) * 4];             \
          ACC = fmaf(W.x, xv.x, ACC); ACC = fmaf(W.y, xv.y, ACC); \
          ACC = fmaf(W.z, xv.z, ACC); ACC = fmaf(W.w, xv.w, ACC); }
      STEP4(w0, 0, a0) STEP4(w1, 1, a1) STEP4(w2, 2, a2) STEP4(w3, 3, a3)
      STEP4(w4, 4, a0) STEP4(w5, 5, a1) STEP4(w6, 6, a2) STEP4(w7, 7, a3)
      STEP4(w8, 8, a0) STEP4(w9, 9, a1) STEP4(wA, 10, a2) STEP4(wB, 11, a3)
      STEP4(wC, 12, a0) STEP4(wD, 13, a1) STEP4(wE, 14, a2) STEP4(wF, 15, a3)
      #undef STEP4
      float acc = (a0 + a1) + (a2 + a3);
      acc += __shfl_xor(acc, 1);   // combine h=0 and h=1 halves

      float inp = 0.f;
      #pragma unroll
      for (int j = 0; j < 6; ++j) inp = fmaf(winp[j], us[cb][ts][j], inp);

      const float pre = acc + inp;
      const float r   = pre > 0.f ? pre : 0.f;
      const float xn  = 0.9f * xr + 0.1f * (r + NOISE_K * rns[cb][ts * NN + i]);
      xr = xn;

      if (h == 0) {
        xbuf[nxt][i + ((i >> 6) << 2)] = xn;  // i<64 -> i ; i>=64 -> 68+(i-64)
        states[((t + 1) * BATCH + b) * NN + i] = f2bf(xn);
      }
      __syncthreads();  // new x visible before next step
    }

    // commit prefetched chunk to the other LDS buffer
    if (c < NCHUNK - 1) {
      *(f32x4*)&rns[cb ^ 1][tid * 4] = rn_pf;
      if (tid < 48) us[cb ^ 1][ts6][j6] = u_pf + NOISE_K * in_pf;
      __syncthreads();
    }
  }
}

// ---------------------------------------------------------------------------
// Kernel 2: states_embedded = states @ q, written transposed: out[j*M + m],
// plus fused W_out rows (jt==0 blocks only).
// Tile: 128 m x 64 j per block, 4 waves, K = 128. q in LDS (bf16, swizzled).
// Epilogue transposes acc through LDS so each half-wave stores 512 B
// contiguous runs (previous version: 64 B segments -> 3.6 TB/s writes).
// ---------------------------------------------------------------------------
__global__ __launch_bounds__(256) void emb_kernel(
    const unsigned short* __restrict__ states,  // (M, n) bf16
    const float* __restrict__ q,                // (n, NEMB)
    const float* __restrict__ W_out,            // (2, n)
    float* __restrict__ out)                    // out[j*M + m]
{
  const int jt  = blockIdx.x;   // 0..15  (fast dim -> j-tiles of one m-panel co-resident)
  const int mt  = blockIdx.y;   // 0..1023
  const int tid = threadIdx.x;
  const int w   = tid >> 6;
  const int l   = tid & 63;
  const int lg  = l >> 4;       // 0..3
  const int lr  = l & 15;

  __shared__ unsigned short qt[64 * 128];  // [j][k], swizzled, 16 KB
  __shared__ float tr[64 * 132];           // [j][m] transpose buffer, 33 KB
  __shared__ float wos[2 * NN];            // W_out rows (used by jt==0)

  // stage q tile -> bf16 LDS (coalesced global reads)
  {
    const int j  = tid & 63;
    const int k0 = tid >> 6;
    #pragma unroll
    for (int kk = k0; kk < 128; kk += 4) {
      float v = q[kk * NEMB + jt * 64 + j];
      int k8 = kk >> 3, e = kk & 7;
      qt[j * 128 + ((k8 ^ (j & 7)) << 3) + e] = f2bf(v);
    }
  }
  if (jt == 0) wos[tid] = W_out[tid];

  // A fragments from global: row = l&15, k-chunk = (l>>4)*8 within each K=32
  s16x8 afrag[2][4];
  #pragma unroll
  for (int mf = 0; mf < 2; ++mf) {
    const int m = mt * 128 + w * 32 + mf * 16 + lr;
    const unsigned short* arow = states + m * NN;
    #pragma unroll
    for (int kc = 0; kc < 4; ++kc)
      afrag[mf][kc] = *(const s16x8*)(arow + kc * 32 + lg * 8);
  }
  __syncthreads();

  f32x4 acc[2][4] = {};
  #pragma unroll
  for (int kc = 0; kc < 4; ++kc) {
    s16x8 bfrag[4];
    #pragma unroll
    for (int jf = 0; jf < 4; ++jf) {
      const int jl = jf * 16 + lr;
      bfrag[jf] = *(const s16x8*)(qt + jl * 128 + ((((kc << 2) + lg) ^ (jl & 7)) << 3));
    }
    #pragma unroll
    for (int mf = 0; mf < 2; ++mf)
      #pragma unroll
      for (int jf = 0; jf < 4; ++jf)
        acc[mf][jf] = __builtin_amdgcn_mfma_f32_16x16x32_bf16(
            afrag[mf][kc], bfrag[jf], acc[mf][jf], 0, 0, 0);
  }

  // fused W_out (jt==0 blocks): per-lane partial over its k-chunks, reduce lg
  if (jt == 0) {
    #pragma unroll
    for (int mf = 0; mf < 2; ++mf) {
      float s0 = 0.f, s1 = 0.f;
      #pragma unroll
      for (int kc = 0; kc < 4; ++kc) {
        const int kb = kc * 32 + lg * 8;
        const s16x8 af = afrag[mf][kc];
        #pragma unroll
        for (int e = 0; e < 8; ++e) {
          const float x = bf2f((unsigned short)af[e]);
          s0 = fmaf(x, wos[kb + e], s0);
          s1 = fmaf(x, wos[NN + kb + e], s1);
        }
      }
      s0 += __shfl_xor(s0, 16); s0 += __shfl_xor(s0, 32);
      s1 += __shfl_xor(s1, 16); s1 += __shfl_xor(s1, 32);
      if (lg == 0) {
        const long m = (long)mt * 128 + w * 32 + mf * 16 + lr;
        out[(long)1024 * M_ROWS + m] = s0;
        out[(long)1025 * M_ROWS + m] = s1;
      }
    }
  }

  // epilogue: acc -> LDS [j][m] -> coalesced stores (512 B runs per j)
  #pragma unroll
  for (int mf = 0; mf < 2; ++mf) {
    const int m0 = w * 32 + mf * 16 + lg * 4;
    #pragma unroll
    for (int jf = 0; jf < 4; ++jf)
      *(f32x4*)&tr[(jf * 16 + lr) * 132 + m0] = acc[mf][jf];
  }
  __syncthreads();

  const int mo = (tid & 31) * 4;
  #pragma unroll
  for (int p = 0; p < 8; ++p) {
    const int jr = p * 8 + (tid >> 5);
    f32x4 v = *(const f32x4*)&tr[jr * 132 + mo];
    *(f32x4*)&out[(long)(jt * 64 + jr) * M_ROWS + mt * 128 + mo] = v;
  }
}

extern "C" void kernel_launch(void* const* d_in, const int* in_sizes, int n_in,
                              void* d_out, int out_size, void* d_ws, size_t ws_size,
                              hipStream_t stream) {
  const float* u         = (const float*)d_in[0];
  const float* rec_noise = (const float*)d_in[1];
  const float* inp_noise = (const float*)d_in[2];
  const float* W_inp     = (const float*)d_in[3];
  const float* W_rec     = (const float*)d_in[4];
  const float* W_out     = (const float*)d_in[5];
  const float* q         = (const float*)d_in[6];
  float* out = (float*)d_out;
  unsigned short* states = (unsigned short*)d_ws;  // (T, B, n) bf16 = 33.6 MB

  rnn_step_kernel<<<dim3(BATCH), dim3(256), 0, stream>>>(
      u, rec_noise, inp_noise, W_inp, W_rec, states);

  dim3 g2(NEMB / 64, M_ROWS / 128);  // (16, 1024), jt fastest for A-panel L2 reuse
  emb_kernel<<<g2, dim3(256), 0, stream>>>(states, q, W_out, out);
}